// Round 1
// baseline (1073.285 us; speedup 1.0000x reference)
//
#include <hip/hip_runtime.h>

typedef _Float16 half8 __attribute__((ext_vector_type(8)));
typedef float floatx4 __attribute__((ext_vector_type(4)));

#define B_EDGES 131072
#define NUSERS  500000
#define NCAS    100000

static __device__ __forceinline__ unsigned short f2h(float f) {
  _Float16 h = (_Float16)f;
  return __builtin_bit_cast(unsigned short, h);
}

// ---------------- init: last_idx = -1, counts = 0 ----------------
__global__ __launch_bounds__(256) void k_init(int* lsrc, int* ldst, int* lcas, int* counts) {
  int i = blockIdx.x * 256 + threadIdx.x;
  if (i < NUSERS) { lsrc[i] = -1; ldst[i] = -1; }
  if (i < NCAS)   lcas[i] = -1;
  if (i < 4)      counts[i] = 0;
}

// ---------------- scatter: last_idx[id] = max batch pos ----------------
__global__ __launch_bounds__(256) void k_scatter(const int* __restrict__ s, const int* __restrict__ d,
                                                 const int* __restrict__ c,
                                                 int* lsrc, int* ldst, int* lcas) {
  int i = blockIdx.x * 256 + threadIdx.x;  // grid exact: 512*256 = 131072
  atomicMax(&lsrc[s[i]], i);
  atomicMax(&ldst[d[i]], i);
  atomicMax(&lcas[c[i]], i);
}

// ---------------- compact active edges per type (wave-aggregated) ----------------
// padded region bounds (multiples of 64 so each wave is region-uniform):
// src: [0, 500032)  dst: [500032, 1000064)  cas: [1000064, 1100064)
__global__ __launch_bounds__(256) void k_compact(const int* __restrict__ lsrc, const int* __restrict__ ldst,
                                                 const int* __restrict__ lcas,
                                                 int* counts, int* list_src, int* list_dst, int* list_cas) {
  int i = blockIdx.x * 256 + threadIdx.x;
  const int* last = nullptr; int* list = nullptr; int* cnt = nullptr; int local = 0; int n = 0;
  if (i < 500032)        { last = lsrc; list = list_src; cnt = counts + 0; local = i;           n = NUSERS; }
  else if (i < 1000064)  { last = ldst; list = list_dst; cnt = counts + 1; local = i - 500032;  n = NUSERS; }
  else if (i < 1100064)  { last = lcas; list = list_cas; cnt = counts + 2; local = i - 1000064; n = NCAS;  }
  int e = (last != nullptr && local < n) ? last[local] : -1;
  bool active = (e >= 0);
  unsigned long long m = __ballot(active);
  if (m) {
    int lane = threadIdx.x & 63;
    int before = __popcll(m & ((1ull << lane) - 1ull));
    int leader = __ffsll((unsigned long long)m) - 1;
    int base = 0;
    if (lane == leader) base = atomicAdd(cnt, __popcll(m));
    base = __shfl(base, leader);
    if (active) list[base + before] = e;
  }
}

// ---------------- fill: zero inactive msg rows, write time/mask ----------------
// 8 rows per 256-block, 32 lanes per row (one float4 each)
__global__ __launch_bounds__(256) void k_fill(const int* __restrict__ lsrc, const int* __restrict__ ldst,
                                              const int* __restrict__ lcas,
                                              const float* __restrict__ et, float* __restrict__ out) {
  int row  = blockIdx.x * 8 + (threadIdx.x >> 5);  // grid exact: 137500*8 = 1,100,000
  int lane = threadIdx.x & 31;
  const int* last; float* msg; float* to; float* ko; int local;
  if (row < 500000)       { local = row;           last = lsrc; msg = out;             to = out + 64000000;  ko = out + 64500000;  }
  else if (row < 1000000) { local = row - 500000;  last = ldst; msg = out + 65000000;  to = out + 129000000; ko = out + 129500000; }
  else                    { local = row - 1000000; last = lcas; msg = out + 130000000; to = out + 142800000; ko = out + 142900000; }
  int e = last[local];
  if (e < 0) {
    float4 z = make_float4(0.f, 0.f, 0.f, 0.f);
    ((float4*)(msg + (size_t)local * 128))[lane] = z;
    if (lane == 0) { to[local] = 0.f; ko[local] = 0.f; }
  } else if (lane == 0) {
    to[local] = et[e]; ko[local] = 1.f;
  }
}

// ---------------- pack W_t (256x128 f32) into f16 MFMA B-fragment order ----------------
// packed[((nt*8+ks)*64+lane)*8 + j] = f16(W[(ks*32 + (lane>>4)*8 + j)*128 + nt*16 + (lane&15)])
__global__ __launch_bounds__(256) void k_pack(const float* __restrict__ Ws, const float* __restrict__ Wd,
                                              const float* __restrict__ Wc, unsigned short* __restrict__ packed) {
  int p = blockIdx.x * 256 + threadIdx.x;  // grid exact: 384*256 = 98304 = 3*32768
  int w = p >> 15, q = p & 32767;
  int j = q & 7, lane = (q >> 3) & 63, ks = (q >> 9) & 7, nt = q >> 12;
  int k = ks * 32 + ((lane >> 4) << 3) + j;
  int n = nt * 16 + (lane & 15);
  const float* W = (w == 0) ? Ws : ((w == 1) ? Wd : Wc);
  packed[p] = f2h(W[k * 128 + n]);
}

// ---------------- message GEMM: 32-row tiles, 16x16x32 f16 MFMA ----------------
// block = 256 threads = 4 waves; wave wv owns cols [wv*32, wv*32+32), both 16-row M-tiles.
// W fragments persistent in registers (64 VGPR/lane); A tile staged in LDS (stride 264 to break conflicts).
__global__ __launch_bounds__(256) void k_msgs(
    const int* __restrict__ sid, const int* __restrict__ did, const int* __restrict__ cid,
    const float* __restrict__ et, const float* __restrict__ pub,
    const float* __restrict__ us, const float* __restrict__ ud, const float* __restrict__ cs,
    const float* __restrict__ ulu,
    const float* __restrict__ wtu, const float* __restrict__ btu,
    const float* __restrict__ wtc, const float* __restrict__ btc,
    const float* __restrict__ bsrc, const float* __restrict__ bdst, const float* __restrict__ bcas,
    const int* __restrict__ counts,
    const int* __restrict__ list_src, const int* __restrict__ list_dst, const int* __restrict__ list_cas,
    const unsigned short* __restrict__ packedW,
    float* __restrict__ out) {
  __shared__ alignas(16) unsigned short A[32][264];
  __shared__ int node_out[32];

  int b = blockIdx.x;
  int type, tile, stride;
  const int* list; const int* oid; const float* wt; const float* bt; const float* bias;
  const unsigned short* pW; float* om; int count;
  if (b < 1024)      { type = 0; tile = b;        stride = 1024; list = list_src; count = counts[0]; oid = sid; wt = wtu; bt = btu; bias = bsrc; pW = packedW;         om = out; }
  else if (b < 2048) { type = 1; tile = b - 1024; stride = 1024; list = list_dst; count = counts[1]; oid = did; wt = wtu; bt = btu; bias = bdst; pW = packedW + 32768; om = out + 65000000; }
  else               { type = 2; tile = b - 2048; stride = 512;  list = list_cas; count = counts[2]; oid = cid; wt = wtc; bt = btc; bias = bcas; pW = packedW + 65536; om = out + 130000000; }

  int tid  = threadIdx.x;
  int lane = tid & 63;
  int wv   = tid >> 6;
  int m_lo = lane & 15;
  int kgrp = lane >> 4;

  // persistent W fragments: wave wv -> N-tiles {2wv, 2wv+1}, 8 K-steps each
  half8 wf[2][8];
  const half8* pw8 = (const half8*)pW;
#pragma unroll
  for (int ntl = 0; ntl < 2; ++ntl)
#pragma unroll
    for (int ks = 0; ks < 8; ++ks)
      wf[ntl][ks] = pw8[((wv * 2 + ntl) * 8 + ks) * 64 + lane];
  float bias0 = bias[wv * 32 + m_lo];
  float bias1 = bias[wv * 32 + 16 + m_lo];

  int tiles = (count + 31) >> 5;
  int r = tid >> 3, t8 = tid & 7;  // 8 staging threads per row

  for (int t = tile; t < tiles; t += stride) {
    __syncthreads();  // protect LDS (and node_out) from previous iteration's readers
    int idx = t * 32 + r;
    if (idx < count) {
      int e = list[idx];
      int s = sid[e], d = did[e], c = cid[e];
      if (t8 == 0) node_out[r] = oid[e];
      // raw 192 cols: 6 float4 per staging thread
#pragma unroll
      for (int i2 = 0; i2 < 6; ++i2) {
        int q = t8 * 6 + i2;
        int col0 = q * 4;
        const float* bp;
        if (col0 < 64)       bp = us + (size_t)s * 64 + col0;
        else if (col0 < 128) bp = ud + (size_t)d * 64 + (col0 - 64);
        else                 bp = cs + (size_t)c * 64 + (col0 - 128);
        float4 v = *(const float4*)bp;
        ushort4 h;
        h.x = f2h(v.x); h.y = f2h(v.y); h.z = f2h(v.z); h.w = f2h(v.w);
        *(ushort4*)&A[r][col0] = h;
      }
      // time encoding cols 192..255: 8 cos per staging thread
      float ete = et[e];
      float dt;
      if (type == 0)      dt = ete - ulu[s];
      else if (type == 1) dt = ete - ulu[d];
      else                dt = ete - pub[e];
      int j0 = t8 * 8;
      ushort4 t0, t1;
      t0.x = f2h(cosf(dt * wt[j0 + 0] + bt[j0 + 0]));
      t0.y = f2h(cosf(dt * wt[j0 + 1] + bt[j0 + 1]));
      t0.z = f2h(cosf(dt * wt[j0 + 2] + bt[j0 + 2]));
      t0.w = f2h(cosf(dt * wt[j0 + 3] + bt[j0 + 3]));
      t1.x = f2h(cosf(dt * wt[j0 + 4] + bt[j0 + 4]));
      t1.y = f2h(cosf(dt * wt[j0 + 5] + bt[j0 + 5]));
      t1.z = f2h(cosf(dt * wt[j0 + 6] + bt[j0 + 6]));
      t1.w = f2h(cosf(dt * wt[j0 + 7] + bt[j0 + 7]));
      *(ushort4*)&A[r][192 + t8 * 8] = t0;
      *(ushort4*)&A[r][196 + t8 * 8] = t1;
    } else {
      ushort4 z; z.x = z.y = z.z = z.w = 0;
#pragma unroll
      for (int i2 = 0; i2 < 6; ++i2) *(ushort4*)&A[r][(t8 * 6 + i2) * 4] = z;
      *(ushort4*)&A[r][192 + t8 * 8] = z;
      *(ushort4*)&A[r][196 + t8 * 8] = z;
      if (t8 == 0) node_out[r] = -1;
    }
    __syncthreads();

    floatx4 acc00 = {0.f, 0.f, 0.f, 0.f}, acc01 = {0.f, 0.f, 0.f, 0.f};
    floatx4 acc10 = {0.f, 0.f, 0.f, 0.f}, acc11 = {0.f, 0.f, 0.f, 0.f};
#pragma unroll
    for (int ks = 0; ks < 8; ++ks) {
      half8 a0 = *(const half8*)&A[m_lo][ks * 32 + kgrp * 8];       // A[m=lane&15][k=kgrp*8+j]
      half8 a1 = *(const half8*)&A[16 + m_lo][ks * 32 + kgrp * 8];
      acc00 = __builtin_amdgcn_mfma_f32_16x16x32_f16(a0, wf[0][ks], acc00, 0, 0, 0);
      acc01 = __builtin_amdgcn_mfma_f32_16x16x32_f16(a0, wf[1][ks], acc01, 0, 0, 0);
      acc10 = __builtin_amdgcn_mfma_f32_16x16x32_f16(a1, wf[0][ks], acc10, 0, 0, 0);
      acc11 = __builtin_amdgcn_mfma_f32_16x16x32_f16(a1, wf[1][ks], acc11, 0, 0, 0);
    }

    // epilogue: D layout col = lane&15, row = kgrp*4 + reg
#pragma unroll
    for (int rg = 0; rg < 4; ++rg) {
      int m0 = kgrp * 4 + rg;
      int n0 = node_out[m0];
      if (n0 >= 0) {
        float* orow = om + (size_t)n0 * 128 + wv * 32 + m_lo;
        orow[0]  = acc00[rg] + bias0;
        orow[16] = acc01[rg] + bias1;
      }
      int n1 = node_out[16 + m0];
      if (n1 >= 0) {
        float* orow = om + (size_t)n1 * 128 + wv * 32 + m_lo;
        orow[0]  = acc10[rg] + bias0;
        orow[16] = acc11[rg] + bias1;
      }
    }
  }
}

extern "C" void kernel_launch(void* const* d_in, const int* in_sizes, int n_in,
                              void* d_out, int out_size, void* d_ws, size_t ws_size,
                              hipStream_t stream) {
  (void)in_sizes; (void)n_in; (void)out_size; (void)ws_size;
  const int*   sid = (const int*)d_in[0];
  const int*   did = (const int*)d_in[1];
  const int*   cid = (const int*)d_in[2];
  const float* et  = (const float*)d_in[3];
  const float* pub = (const float*)d_in[4];
  const float* us  = (const float*)d_in[5];
  const float* ud  = (const float*)d_in[6];
  const float* cs  = (const float*)d_in[7];
  const float* ulu = (const float*)d_in[8];
  const float* wtu = (const float*)d_in[9];
  const float* btu = (const float*)d_in[10];
  const float* wtc = (const float*)d_in[11];
  const float* btc = (const float*)d_in[12];
  const float* Ws  = (const float*)d_in[13];
  const float* bs  = (const float*)d_in[14];
  const float* Wd  = (const float*)d_in[15];
  const float* bd  = (const float*)d_in[16];
  const float* Wc  = (const float*)d_in[17];
  const float* bc  = (const float*)d_in[18];
  float* out = (float*)d_out;

  int* wsI       = (int*)d_ws;
  int* lsrc      = wsI;
  int* ldst      = wsI + 500000;
  int* lcas      = wsI + 1000000;
  int* counts    = wsI + 1100000;   // 4 ints
  int* list_src  = wsI + 1100004;   // 131072
  int* list_dst  = wsI + 1231076;   // 131072
  int* list_cas  = wsI + 1362148;   // 100000
  unsigned short* packedW = (unsigned short*)(wsI + 1462148);  // 3*32768 u16, 16B-aligned

  k_init<<<1954, 256, 0, stream>>>(lsrc, ldst, lcas, counts);
  k_scatter<<<512, 256, 0, stream>>>(sid, did, cid, lsrc, ldst, lcas);
  k_compact<<<4298, 256, 0, stream>>>(lsrc, ldst, lcas, counts, list_src, list_dst, list_cas);
  k_fill<<<137500, 256, 0, stream>>>(lsrc, ldst, lcas, et, out);
  k_pack<<<384, 256, 0, stream>>>(Ws, Wd, Wc, packedW);
  k_msgs<<<2560, 256, 0, stream>>>(sid, did, cid, et, pub, us, ud, cs, ulu,
                                   wtu, btu, wtc, btc, bs, bd, bc,
                                   counts, list_src, list_dst, list_cas, packedW, out);
}

// Round 2
// 1005.265 us; speedup vs baseline: 1.0677x; 1.0677x over previous
//
#include <hip/hip_runtime.h>

typedef _Float16 half8 __attribute__((ext_vector_type(8)));
typedef float floatx4 __attribute__((ext_vector_type(4)));

#define B_EDGES 131072
#define NUSERS  500000
#define NCAS    100000

static __device__ __forceinline__ unsigned short f2h(float f) {
  _Float16 h = (_Float16)f;
  return __builtin_bit_cast(unsigned short, h);
}

static __device__ __forceinline__ half8 pack8(float4 a, float4 b) {
  half8 h;
  h[0] = (_Float16)a.x; h[1] = (_Float16)a.y; h[2] = (_Float16)a.z; h[3] = (_Float16)a.w;
  h[4] = (_Float16)b.x; h[5] = (_Float16)b.y; h[6] = (_Float16)b.z; h[7] = (_Float16)b.w;
  return h;
}

// ---------------- init last_idx = -1, counts = 0; pack W into f16 B-fragments ----------------
// packed[((nt*8+ks)*64+lane)*8 + j] = f16(W[(ks*32 + (lane>>4)*8 + j)*128 + nt*16 + (lane&15)])
__global__ __launch_bounds__(256) void k_init(int* lsrc, int* ldst, int* lcas, int* counts,
                                              const float* __restrict__ Ws, const float* __restrict__ Wd,
                                              const float* __restrict__ Wc, unsigned short* __restrict__ packed) {
  int i = blockIdx.x * 256 + threadIdx.x;
  if (i < NUSERS) { lsrc[i] = -1; ldst[i] = -1; }
  if (i < NCAS)   lcas[i] = -1;
  if (i < 4)      counts[i] = 0;
  if (i < 98304) {
    int w = i >> 15, q = i & 32767;
    int j = q & 7, lane = (q >> 3) & 63, ks = (q >> 9) & 7, nt = q >> 12;
    int k = ks * 32 + ((lane >> 4) << 3) + j;
    int n = nt * 16 + (lane & 15);
    const float* W = (w == 0) ? Ws : ((w == 1) ? Wd : Wc);
    packed[i] = f2h(W[k * 128 + n]);
  }
}

// ---------------- scatter: last_idx[id] = max batch pos ----------------
__global__ __launch_bounds__(256) void k_scatter(const int* __restrict__ s, const int* __restrict__ d,
                                                 const int* __restrict__ c,
                                                 int* lsrc, int* ldst, int* lcas) {
  int i = blockIdx.x * 256 + threadIdx.x;  // grid exact: 512*256 = 131072
  atomicMax(&lsrc[s[i]], i);
  atomicMax(&ldst[d[i]], i);
  atomicMax(&lcas[c[i]], i);
}

// ---------------- compact active edges per type (wave-aggregated) ----------------
// padded region bounds (multiples of 64 so each wave is region-uniform):
// src: [0, 500032)  dst: [500032, 1000064)  cas: [1000064, 1100064)
__global__ __launch_bounds__(256) void k_compact(const int* __restrict__ lsrc, const int* __restrict__ ldst,
                                                 const int* __restrict__ lcas,
                                                 int* counts, int* list_src, int* list_dst, int* list_cas) {
  int i = blockIdx.x * 256 + threadIdx.x;
  const int* last = nullptr; int* list = nullptr; int* cnt = nullptr; int local = 0; int n = 0;
  if (i < 500032)        { last = lsrc; list = list_src; cnt = counts + 0; local = i;           n = NUSERS; }
  else if (i < 1000064)  { last = ldst; list = list_dst; cnt = counts + 1; local = i - 500032;  n = NUSERS; }
  else if (i < 1100064)  { last = lcas; list = list_cas; cnt = counts + 2; local = i - 1000064; n = NCAS;  }
  int e = (last != nullptr && local < n) ? last[local] : -1;
  bool active = (e >= 0);
  unsigned long long m = __ballot(active);
  if (m) {
    int lane = threadIdx.x & 63;
    int before = __popcll(m & ((1ull << lane) - 1ull));
    int leader = __ffsll((unsigned long long)m) - 1;
    int base = 0;
    if (lane == leader) base = atomicAdd(cnt, __popcll(m));
    base = __shfl(base, leader);
    if (active) list[base + before] = e;
  }
}

// ---------------- fill: zero inactive msg rows, write time/mask ----------------
// 8 rows per 256-block, 32 lanes per row (one float4 each)
__global__ __launch_bounds__(256) void k_fill(const int* __restrict__ lsrc, const int* __restrict__ ldst,
                                              const int* __restrict__ lcas,
                                              const float* __restrict__ et, float* __restrict__ out) {
  int row  = blockIdx.x * 8 + (threadIdx.x >> 5);  // grid exact: 137500*8 = 1,100,000
  int lane = threadIdx.x & 31;
  const int* last; float* msg; float* to; float* ko; int local;
  if (row < 500000)       { local = row;           last = lsrc; msg = out;             to = out + 64000000;  ko = out + 64500000;  }
  else if (row < 1000000) { local = row - 500000;  last = ldst; msg = out + 65000000;  to = out + 129000000; ko = out + 129500000; }
  else                    { local = row - 1000000; last = lcas; msg = out + 130000000; to = out + 142800000; ko = out + 142900000; }
  int e = last[local];
  if (e < 0) {
    float4 z = make_float4(0.f, 0.f, 0.f, 0.f);
    ((float4*)(msg + (size_t)local * 128))[lane] = z;
    if (lane == 0) { to[local] = 0.f; ko[local] = 0.f; }
  } else if (lane == 0) {
    to[local] = et[e]; ko[local] = 1.f;
  }
}

// ---------------- message GEMM: 32-row tiles, 16x16x32 f16 MFMA ----------------
// block = 256 threads = 4 waves; wave wv owns cols [wv*32, wv*32+32), both 16-row M-tiles.
// W fragments persistent in registers (64 VGPR/lane); A tile staged in LDS (stride 264 halfs).
// Staging: 8 threads/row; thread t8 loads float4 pair (t8*2, t8*2+1) from EACH of us/ud/cs
// (loop-uniform array -> no divergent pointer select) and computes 8 native-cos time cols.
__global__ __launch_bounds__(256, 3) void k_msgs(
    const int* __restrict__ sid, const int* __restrict__ did, const int* __restrict__ cid,
    const float* __restrict__ et, const float* __restrict__ pub,
    const float* __restrict__ us, const float* __restrict__ ud, const float* __restrict__ cs,
    const float* __restrict__ ulu,
    const float* __restrict__ wtu, const float* __restrict__ btu,
    const float* __restrict__ wtc, const float* __restrict__ btc,
    const float* __restrict__ bsrc, const float* __restrict__ bdst, const float* __restrict__ bcas,
    const int* __restrict__ counts,
    const int* __restrict__ list_src, const int* __restrict__ list_dst, const int* __restrict__ list_cas,
    const unsigned short* __restrict__ packedW,
    float* __restrict__ out) {
  __shared__ alignas(16) unsigned short A[32][264];
  __shared__ int node_out[32];

  int b = blockIdx.x;
  int type, tile, stride;
  const int* list; const int* oid; const float* wt; const float* bt; const float* bias;
  const unsigned short* pW; float* om; int count;
  if (b < 1024)      { type = 0; tile = b;        stride = 1024; list = list_src; count = counts[0]; oid = sid; wt = wtu; bt = btu; bias = bsrc; pW = packedW;         om = out; }
  else if (b < 2048) { type = 1; tile = b - 1024; stride = 1024; list = list_dst; count = counts[1]; oid = did; wt = wtu; bt = btu; bias = bdst; pW = packedW + 32768; om = out + 65000000; }
  else               { type = 2; tile = b - 2048; stride = 512;  list = list_cas; count = counts[2]; oid = cid; wt = wtc; bt = btc; bias = bcas; pW = packedW + 65536; om = out + 130000000; }

  int tid  = threadIdx.x;
  int lane = tid & 63;
  int wv   = tid >> 6;
  int m_lo = lane & 15;
  int kgrp = lane >> 4;

  // persistent W fragments: wave wv -> N-tiles {2wv, 2wv+1}, 8 K-steps each
  half8 wf[2][8];
  const half8* pw8 = (const half8*)pW;
#pragma unroll
  for (int ntl = 0; ntl < 2; ++ntl)
#pragma unroll
    for (int ks = 0; ks < 8; ++ks)
      wf[ntl][ks] = pw8[((wv * 2 + ntl) * 8 + ks) * 64 + lane];
  float bias0 = bias[wv * 32 + m_lo];
  float bias1 = bias[wv * 32 + 16 + m_lo];

  int r = tid >> 3, t8 = tid & 7;  // 8 staging threads per row
  // hoisted per-thread time-encoder coefficients (cols t8*8 .. t8*8+7)
  float4 w4a = ((const float4*)wt)[t8 * 2];
  float4 w4b = ((const float4*)wt)[t8 * 2 + 1];
  float4 b4a = ((const float4*)bt)[t8 * 2];
  float4 b4b = ((const float4*)bt)[t8 * 2 + 1];

  int tiles = (count + 31) >> 5;

  for (int t = tile; t < tiles; t += stride) {
    __syncthreads();  // protect LDS from previous iteration's readers
    int idx = t * 32 + r;
    int e = (idx < count) ? list[idx] : -1;
    if (e >= 0) {
      int s = sid[e], d = did[e], c = cid[e];
      if (t8 == 0) node_out[r] = oid[e];
      const float* base0 = us + (size_t)s * 64;
      const float* base1 = ud + (size_t)d * 64;
      const float* base2 = cs + (size_t)c * 64;
#pragma unroll
      for (int a = 0; a < 3; ++a) {
        const float* bp = (a == 0) ? base0 : ((a == 1) ? base1 : base2);
        float4 v0 = ((const float4*)bp)[t8 * 2];
        float4 v1 = ((const float4*)bp)[t8 * 2 + 1];
        *(half8*)&A[r][a * 64 + t8 * 8] = pack8(v0, v1);
      }
      float ete = et[e];
      float dt;
      if (type == 0)      dt = ete - ulu[s];
      else if (type == 1) dt = ete - ulu[d];
      else                dt = ete - pub[e];
      float4 c0, c1;
      c0.x = __cosf(dt * w4a.x + b4a.x);
      c0.y = __cosf(dt * w4a.y + b4a.y);
      c0.z = __cosf(dt * w4a.z + b4a.z);
      c0.w = __cosf(dt * w4a.w + b4a.w);
      c1.x = __cosf(dt * w4b.x + b4b.x);
      c1.y = __cosf(dt * w4b.y + b4b.y);
      c1.z = __cosf(dt * w4b.z + b4b.z);
      c1.w = __cosf(dt * w4b.w + b4b.w);
      *(half8*)&A[r][192 + t8 * 8] = pack8(c0, c1);
    } else {
      half8 z = {0, 0, 0, 0, 0, 0, 0, 0};
#pragma unroll
      for (int a = 0; a < 3; ++a) *(half8*)&A[r][a * 64 + t8 * 8] = z;
      *(half8*)&A[r][192 + t8 * 8] = z;
      if (t8 == 0) node_out[r] = -1;
    }
    __syncthreads();

    floatx4 acc00 = {0.f, 0.f, 0.f, 0.f}, acc01 = {0.f, 0.f, 0.f, 0.f};
    floatx4 acc10 = {0.f, 0.f, 0.f, 0.f}, acc11 = {0.f, 0.f, 0.f, 0.f};
#pragma unroll
    for (int ks = 0; ks < 8; ++ks) {
      half8 a0 = *(const half8*)&A[m_lo][ks * 32 + kgrp * 8];       // A[m=lane&15][k=kgrp*8+j]
      half8 a1 = *(const half8*)&A[16 + m_lo][ks * 32 + kgrp * 8];
      acc00 = __builtin_amdgcn_mfma_f32_16x16x32_f16(a0, wf[0][ks], acc00, 0, 0, 0);
      acc01 = __builtin_amdgcn_mfma_f32_16x16x32_f16(a0, wf[1][ks], acc01, 0, 0, 0);
      acc10 = __builtin_amdgcn_mfma_f32_16x16x32_f16(a1, wf[0][ks], acc10, 0, 0, 0);
      acc11 = __builtin_amdgcn_mfma_f32_16x16x32_f16(a1, wf[1][ks], acc11, 0, 0, 0);
    }

    // epilogue: D layout col = lane&15, row = kgrp*4 + reg
#pragma unroll
    for (int rg = 0; rg < 4; ++rg) {
      int m0 = kgrp * 4 + rg;
      int n0 = node_out[m0];
      if (n0 >= 0) {
        float* orow = om + (size_t)n0 * 128 + wv * 32 + m_lo;
        orow[0]  = acc00[rg] + bias0;
        orow[16] = acc01[rg] + bias1;
      }
      int n1 = node_out[16 + m0];
      if (n1 >= 0) {
        float* orow = om + (size_t)n1 * 128 + wv * 32 + m_lo;
        orow[0]  = acc10[rg] + bias0;
        orow[16] = acc11[rg] + bias1;
      }
    }
  }
}

extern "C" void kernel_launch(void* const* d_in, const int* in_sizes, int n_in,
                              void* d_out, int out_size, void* d_ws, size_t ws_size,
                              hipStream_t stream) {
  (void)in_sizes; (void)n_in; (void)out_size; (void)ws_size;
  const int*   sid = (const int*)d_in[0];
  const int*   did = (const int*)d_in[1];
  const int*   cid = (const int*)d_in[2];
  const float* et  = (const float*)d_in[3];
  const float* pub = (const float*)d_in[4];
  const float* us  = (const float*)d_in[5];
  const float* ud  = (const float*)d_in[6];
  const float* cs  = (const float*)d_in[7];
  const float* ulu = (const float*)d_in[8];
  const float* wtu = (const float*)d_in[9];
  const float* btu = (const float*)d_in[10];
  const float* wtc = (const float*)d_in[11];
  const float* btc = (const float*)d_in[12];
  const float* Ws  = (const float*)d_in[13];
  const float* bs  = (const float*)d_in[14];
  const float* Wd  = (const float*)d_in[15];
  const float* bd  = (const float*)d_in[16];
  const float* Wc  = (const float*)d_in[17];
  const float* bc  = (const float*)d_in[18];
  float* out = (float*)d_out;

  int* wsI       = (int*)d_ws;
  int* lsrc      = wsI;
  int* ldst      = wsI + 500000;
  int* lcas      = wsI + 1000000;
  int* counts    = wsI + 1100000;   // 4 ints
  int* list_src  = wsI + 1100004;   // 131072
  int* list_dst  = wsI + 1231076;   // 131072
  int* list_cas  = wsI + 1362148;   // 100000
  unsigned short* packedW = (unsigned short*)(wsI + 1462148);  // 3*32768 u16, 16B-aligned

  k_init<<<1954, 256, 0, stream>>>(lsrc, ldst, lcas, counts, Ws, Wd, Wc, packedW);
  k_scatter<<<512, 256, 0, stream>>>(sid, did, cid, lsrc, ldst, lcas);
  k_compact<<<4298, 256, 0, stream>>>(lsrc, ldst, lcas, counts, list_src, list_dst, list_cas);
  k_fill<<<137500, 256, 0, stream>>>(lsrc, ldst, lcas, et, out);
  k_msgs<<<2560, 256, 0, stream>>>(sid, did, cid, et, pub, us, ud, cs, ulu,
                                   wtu, btu, wtc, btc, bs, bd, bc,
                                   counts, list_src, list_dst, list_cas, packedW, out);
}